// Round 1
// 211.494 us; speedup vs baseline: 1.0340x; 1.0340x over previous
//
#include <hip/hip_runtime.h>
#include <hip/hip_bf16.h>
#include <cstdint>

// Problem: out = x @ (W + scale*B@A)^T + b
//   x[4,2048,2048] -> X[M=8192, K=2048],  W[N=2048, K=2048], b[N],
//   A[R=16, K], B[N, R=16], scale scalar.  ALL I/O IS FLOAT32.
// Pipeline: fused (cvt x->bf16 + fold LoRA into bf16 W_eff), one MFMA GEMM.
// R4: BK=64 + XOR bank swizzle  -> 88.7 us GEMM, 0 bank conflicts.
// R5: XCD-rectangle block swizzle (L2 locality) + fused aux kernel.
// R6: 256x256 8-phase GEMM (T2+T3+T4+T5): 512 thr / 8 waves (2Mx4N),
//     128 KiB dbuf LDS in K-half regions, counted vmcnt(8) (never 0),
//     raw s_barrier (no compiler drain), setprio around MFMA clusters.

typedef __bf16 bf16x8 __attribute__((ext_vector_type(8)));
typedef float floatx4 __attribute__((ext_vector_type(4)));
typedef unsigned short ushort8 __attribute__((ext_vector_type(8)));

#define BM 256
#define BN 256
#define BK 64

__device__ __forceinline__ void gload_lds16(const void* g, void* l) {
    // 16B-per-lane async global->LDS. LDS dest must be wave-uniform base + lane*16.
    __builtin_amdgcn_global_load_lds((__attribute__((address_space(1))) void*)g,
                                     (__attribute__((address_space(3))) void*)l,
                                     16, 0, 0);
}

// fp32 -> bf16 bits, round-to-nearest-even (finite inputs only).
__device__ __forceinline__ unsigned short f2bf_bits(float f) {
    unsigned int u = __float_as_uint(f);
    u += 0x7FFFu + ((u >> 16) & 1u);
    return (unsigned short)(u >> 16);
}

// ---------------------------------------------------------------------------
// Fused aux kernel.
//   blocks [0, 8192):      Xbf = bf16(x)         (8 elems/thread)
//   blocks [8192, 10240):  Weff = bf16(W + scale*B@A)
// ---------------------------------------------------------------------------
__global__ __launch_bounds__(256)
void aux_kernel(const float* __restrict__ x, unsigned short* __restrict__ Xbf,
                const float* __restrict__ W, const float* __restrict__ A,
                const float* __restrict__ Bm, const float* __restrict__ scale_p,
                unsigned short* __restrict__ Weff)
{
    const int K = 2048, R = 16;
    int bid = blockIdx.x;
    if (bid < 8192) {
        size_t i = ((size_t)bid * 256 + threadIdx.x) * 8;
        float4 a = *reinterpret_cast<const float4*>(x + i);
        float4 b = *reinterpret_cast<const float4*>(x + i + 4);
        ushort8 o;
        o[0] = f2bf_bits(a.x); o[1] = f2bf_bits(a.y);
        o[2] = f2bf_bits(a.z); o[3] = f2bf_bits(a.w);
        o[4] = f2bf_bits(b.x); o[5] = f2bf_bits(b.y);
        o[6] = f2bf_bits(b.z); o[7] = f2bf_bits(b.w);
        *reinterpret_cast<ushort8*>(Xbf + i) = o;
    } else {
        int t  = (bid - 8192) * 256 + threadIdx.x;
        int n  = t >> 8;
        int k8 = (t & 255) << 3;

        float s = *scale_p;
        float br[16];
#pragma unroll
        for (int r = 0; r < R; ++r)
            br[r] = s * Bm[n * R + r];

        float acc[8] = {0,0,0,0,0,0,0,0};
#pragma unroll
        for (int r = 0; r < R; ++r) {
            const float* ap = A + r * K + k8;
#pragma unroll
            for (int j = 0; j < 8; ++j)
                acc[j] += br[r] * ap[j];
        }

        const float* wp = W + (size_t)n * K + k8;
        ushort8 o;
#pragma unroll
        for (int j = 0; j < 8; ++j)
            o[j] = f2bf_bits(wp[j] + acc[j]);
        *reinterpret_cast<ushort8*>(Weff + (size_t)n * K + k8) = o;
    }
}

// ---------------------------------------------------------------------------
// GEMM: out[M,N] (fp32) = Xbf[M,K] @ Weffbf[N,K]^T + bias (fp32)
// 256x256 tile, BK=64, 8 waves (2x4), 8-phase schedule, counted vmcnt.
//
// LDS: Sa/Sb[buf][khalf][256 rows][32 cols bf16]  (16 KB per region).
// Swizzle (involution, both sides): slot(0..3 of 16B) ^= (row>>1)&3.
// Stage set = one region = 2 gload_lds/thread (chunk c = l*512+tid,
//   row = c>>2, slot = c&3; global col pre-swizzled, LDS dest linear).
//
// Per K-tile t, 4 phases (quadrant = kslice x nhalf), each 16 MFMA:
//   c1 (ks0,n0): read af[8]+bf[2]; stage A-kh1(t+1)
//   c2 (ks0,n1): read bf[2];       stage B-kh1(t+1); vmcnt(8)
//   c3 (ks1,n0): read af[8]+bf[2]; stage A-kh0(t+2)
//   c4 (ks1,n1): read bf[2];       stage B-kh0(t+2); vmcnt(8)
// Each phase: reads; stage; s_barrier; lgkmcnt(0); setprio(1); MFMA;
// setprio(0); [vmcnt(8)] s_barrier.  4 half-tiles (8 loads/thread) stay
// in flight; each vmcnt(8) retires exactly the 2 regions the next two
// phases read (hand-verified incl. prologue + clamped epilogue).
// ---------------------------------------------------------------------------
#define BAR()       __builtin_amdgcn_s_barrier()
#define WAIT_LGKM() asm volatile("s_waitcnt lgkmcnt(0)" ::: "memory")
#define WAIT_VM8()  asm volatile("s_waitcnt vmcnt(8)" ::: "memory")

#define STAGE(Ldst, Gsrc, koff) do {                                          \
    gload_lds16((Gsrc) + (koff),                   (Ldst) + tid * 8);         \
    gload_lds16((Gsrc) + (size_t)128 * K + (koff), (Ldst) + 4096 + tid * 8);  \
} while (0)

#define READ_A(buf, ks)                                                       \
    _Pragma("unroll")                                                         \
    for (int mi = 0; mi < 8; ++mi)                                            \
        af[mi] = *reinterpret_cast<const bf16x8*>(                            \
            &Sa[buf][ks][(arow + mi * 16) * 32 + aswz]);

#define READ_B(buf, ks, nh)                                                   \
    _Pragma("unroll")                                                         \
    for (int ni = 0; ni < 2; ++ni)                                            \
        bf[ni] = *reinterpret_cast<const bf16x8*>(                            \
            &Sb[buf][ks][(brow + (nh) * 32 + ni * 16) * 32 + aswz]);

#define MFMA_HALF(nh) do {                                                    \
    __builtin_amdgcn_s_setprio(1);                                            \
    _Pragma("unroll")                                                         \
    for (int mi = 0; mi < 8; ++mi) {                                          \
        acc[mi][(nh)*2+0] = __builtin_amdgcn_mfma_f32_16x16x32_bf16(          \
            af[mi], bf[0], acc[mi][(nh)*2+0], 0, 0, 0);                       \
        acc[mi][(nh)*2+1] = __builtin_amdgcn_mfma_f32_16x16x32_bf16(          \
            af[mi], bf[1], acc[mi][(nh)*2+1], 0, 0, 0);                       \
    }                                                                         \
    __builtin_amdgcn_s_setprio(0);                                            \
} while (0)

#define TILE(buf, kA, kB) do {                                                \
    /* c1: ks0, n-half 0 */                                                   \
    READ_A(buf, 0); READ_B(buf, 0, 0);                                        \
    STAGE(&Sa[1-(buf)][1][0], gA, (kA));                                      \
    BAR(); WAIT_LGKM(); MFMA_HALF(0); BAR();                                  \
    /* c2: ks0, n-half 1 */                                                   \
    READ_B(buf, 0, 1);                                                        \
    STAGE(&Sb[1-(buf)][1][0], gB, (kA));                                      \
    BAR(); WAIT_LGKM(); MFMA_HALF(1); WAIT_VM8(); BAR();                      \
    /* c3: ks1, n-half 0 */                                                   \
    READ_A(buf, 1); READ_B(buf, 1, 0);                                        \
    STAGE(&Sa[buf][0][0], gA, (kB));                                          \
    BAR(); WAIT_LGKM(); MFMA_HALF(0); BAR();                                  \
    /* c4: ks1, n-half 1 */                                                   \
    READ_B(buf, 1, 1);                                                        \
    STAGE(&Sb[buf][0][0], gB, (kB));                                          \
    BAR(); WAIT_LGKM(); MFMA_HALF(1); WAIT_VM8(); BAR();                      \
} while (0)

__global__ __launch_bounds__(512)
void gemm_bias_kernel(const unsigned short* __restrict__ X,
                      const unsigned short* __restrict__ Wt,
                      const float* __restrict__ bias,
                      float* __restrict__ out)
{
    const int N = 2048, K = 2048, NT = 32;

    __shared__ alignas(16) unsigned short Sa[2][2][256 * 32];  // 64 KB
    __shared__ alignas(16) unsigned short Sb[2][2][256 * 32];  // 64 KB

    const int tid  = threadIdx.x;
    const int wave = tid >> 6;
    const int lane = tid & 63;
    const int lrow = lane & 15;
    const int quad = lane >> 4;
    const int wr   = wave >> 2;   // 0..1  (M split)
    const int wc   = wave & 3;    // 0..3  (N split)

    // XCD-rectangle swizzle: id%8 -> XCD; XCD k owns m-stripes [4k,4k+4) x all
    // 8 n-tiles => per-XCD X footprint 4 MB (fits its L2). Bijective (256%8==0).
    const int id  = blockIdx.x;            // 0..255
    const int xcd = id & 7;
    const int sg  = id >> 3;               // 0..31
    const int bm  = (xcd * 4 + (sg & 3)) * BM;
    const int bn  = (sg >> 2) * BN;

    // Staging geometry: region chunk c = l*512 + tid; row = c>>2, slot = c&3.
    // For l=1, row = srow+128 and the swizzle term is unchanged ((r+128)>>1 &3
    // == (r>>1)&3), so source is just +128*K.
    const int srow  = tid >> 2;                          // 0..127
    const int sslot = tid & 3;
    const int sgcol = (sslot ^ ((srow >> 1) & 3)) << 3;  // pre-swizzled col
    const unsigned short* gA = X  + (size_t)(bm + srow) * K + sgcol;
    const unsigned short* gB = Wt + (size_t)(bn + srow) * K + sgcol;

    floatx4 acc[8][4] = {};
    bf16x8 af[8], bf[2];

    // ds_read addressing: row*64B + swizzled-slot*16B. (row>>1)&3 ==
    // (lrow>>1)&3 for all frag rows (wr*128, mi*16, nh*32, ni*16 are =0 mod 8).
    const int aswz = (quad ^ ((lrow >> 1) & 3)) << 3;    // ushort offset
    const int arow = wr * 128 + lrow;
    const int brow = wc * 64 + lrow;

    // Prologue: sigma1/2(0), sigma3/4(0), sigma1/2(1); vmcnt(8) lands the
    // first two (tile0 kh0) -> matches steady-state wait pattern.
    STAGE(&Sa[0][0][0], gA, 0);
    STAGE(&Sb[0][0][0], gB, 0);
    STAGE(&Sa[0][1][0], gA, 32);
    STAGE(&Sb[0][1][0], gB, 32);
    STAGE(&Sa[1][0][0], gA, 64);
    STAGE(&Sb[1][0][0], gB, 64);
    WAIT_VM8(); BAR();

#pragma unroll 1
    for (int tt = 0; tt < NT; tt += 2) {
        // stage k-offsets (clamped past the last tile: re-reads are L2-hot
        // and land in regions whose last read is already barrier-complete).
        const int ka0 = (tt + 1 < NT ? tt + 1 : NT - 1) * BK + 32;  // A/B-kh1(t+1)
        const int kb0 = (tt + 2 < NT ? tt + 2 : NT - 1) * BK;       // A/B-kh0(t+2)
        const int ka1 = (tt + 2 < NT ? tt + 2 : NT - 1) * BK + 32;
        const int kb1 = (tt + 3 < NT ? tt + 3 : NT - 1) * BK;
        TILE(0, ka0, kb0);
        TILE(1, ka1, kb1);
    }
    asm volatile("s_waitcnt vmcnt(0)" ::: "memory");  // drain before endpgm

    // Epilogue. C/D layout (m89/m91): col = lane&15, row = (lane>>4)*4 + reg.
    float bsv[4];
#pragma unroll
    for (int ni = 0; ni < 4; ++ni)
        bsv[ni] = bias[bn + wc * 64 + ni * 16 + lrow];

    const int rbase = quad << 2;
#pragma unroll
    for (int mi = 0; mi < 8; ++mi) {
#pragma unroll
        for (int r = 0; r < 4; ++r) {
            size_t rowoff = (size_t)(bm + wr * 128 + mi * 16 + rbase + r) * N;
#pragma unroll
            for (int ni = 0; ni < 4; ++ni)
                out[rowoff + bn + wc * 64 + ni * 16 + lrow] = acc[mi][ni][r] + bsv[ni];
        }
    }
}

extern "C" void kernel_launch(void* const* d_in, const int* in_sizes, int n_in,
                              void* d_out, int out_size, void* d_ws, size_t ws_size,
                              hipStream_t stream)
{
    const float* x  = (const float*)d_in[0];
    const float* W  = (const float*)d_in[1];
    const float* b  = (const float*)d_in[2];
    const float* A  = (const float*)d_in[3];
    const float* Bm = (const float*)d_in[4];
    const float* sc = (const float*)d_in[5];
    float* out = (float*)d_out;

    const size_t M = 8192, N = 2048, K = 2048;

    unsigned short* Xbf  = (unsigned short*)d_ws;                 // 32 MB
    unsigned short* Weff = (unsigned short*)d_ws + M * K;         // + 8 MB

    // 1) fused: Xbf = bf16(x); Weff = bf16(W + scale * B@A)
    aux_kernel<<<dim3((M * K + N * K) / 8 / 256), dim3(256), 0, stream>>>(
        x, Xbf, W, A, Bm, sc, Weff);

    // 2) out = Xbf @ Weff^T + b  (fp32 out), 256 blocks = 256 CUs, no tails
    gemm_bias_kernel<<<dim3((M / BM) * (N / BN)), dim3(512), 0, stream>>>(
        Xbf, Weff, b, out);
}

// Round 2
// 207.495 us; speedup vs baseline: 1.0540x; 1.0193x over previous
//
#include <hip/hip_runtime.h>
#include <hip/hip_bf16.h>
#include <cstdint>

// Problem: out = x @ (W + scale*B@A)^T + b
//   x[4,2048,2048] -> X[M=8192, K=2048],  W[N=2048, K=2048], b[N],
//   A[R=16, K], B[N, R=16], scale scalar.  ALL I/O IS FLOAT32.
// Pipeline: fused (cvt x->bf16 + fold LoRA into bf16 W_eff), one MFMA GEMM.
// R6: 256x256 8-phase GEMM, counted vmcnt -> 77us, MfmaUtil 36% (phase
//     imbalance 10/2/10/2 + burst staging defeated the lgkm stagger).
// R7: faithful m201 cadence: Gray-code C-quadrants (full K=64 per phase,
//     dependent kslice MFMA pairs), uniform 1 half-tile staged per phase,
//     vmcnt(4) only at phases 4 and 8, A split by M-half / B by N-half.

typedef __bf16 bf16x8 __attribute__((ext_vector_type(8)));
typedef float floatx4 __attribute__((ext_vector_type(4)));
typedef unsigned short ushort8 __attribute__((ext_vector_type(8)));

#define BM 256
#define BN 256
#define BK 64
#define NT 32   // K / BK

__device__ __forceinline__ void gload_lds16(const void* g, void* l) {
    // 16B-per-lane async global->LDS. LDS dest must be wave-uniform base + lane*16.
    __builtin_amdgcn_global_load_lds((__attribute__((address_space(1))) void*)g,
                                     (__attribute__((address_space(3))) void*)l,
                                     16, 0, 0);
}

// fp32 -> bf16 bits, round-to-nearest-even (finite inputs only).
__device__ __forceinline__ unsigned short f2bf_bits(float f) {
    unsigned int u = __float_as_uint(f);
    u += 0x7FFFu + ((u >> 16) & 1u);
    return (unsigned short)(u >> 16);
}

// ---------------------------------------------------------------------------
// Fused aux kernel (unchanged).
//   blocks [0, 8192):      Xbf = bf16(x)
//   blocks [8192, 10240):  Weff = bf16(W + scale*B@A)
// ---------------------------------------------------------------------------
__global__ __launch_bounds__(256)
void aux_kernel(const float* __restrict__ x, unsigned short* __restrict__ Xbf,
                const float* __restrict__ W, const float* __restrict__ A,
                const float* __restrict__ Bm, const float* __restrict__ scale_p,
                unsigned short* __restrict__ Weff)
{
    const int K = 2048, R = 16;
    int bid = blockIdx.x;
    if (bid < 8192) {
        size_t i = ((size_t)bid * 256 + threadIdx.x) * 8;
        float4 a = *reinterpret_cast<const float4*>(x + i);
        float4 b = *reinterpret_cast<const float4*>(x + i + 4);
        ushort8 o;
        o[0] = f2bf_bits(a.x); o[1] = f2bf_bits(a.y);
        o[2] = f2bf_bits(a.z); o[3] = f2bf_bits(a.w);
        o[4] = f2bf_bits(b.x); o[5] = f2bf_bits(b.y);
        o[6] = f2bf_bits(b.z); o[7] = f2bf_bits(b.w);
        *reinterpret_cast<ushort8*>(Xbf + i) = o;
    } else {
        int t  = (bid - 8192) * 256 + threadIdx.x;
        int n  = t >> 8;
        int k8 = (t & 255) << 3;

        float s = *scale_p;
        float br[16];
#pragma unroll
        for (int r = 0; r < R; ++r)
            br[r] = s * Bm[n * R + r];

        float acc[8] = {0,0,0,0,0,0,0,0};
#pragma unroll
        for (int r = 0; r < R; ++r) {
            const float* ap = A + r * K + k8;
#pragma unroll
            for (int j = 0; j < 8; ++j)
                acc[j] += br[r] * ap[j];
        }

        const float* wp = W + (size_t)n * K + k8;
        ushort8 o;
#pragma unroll
        for (int j = 0; j < 8; ++j)
            o[j] = f2bf_bits(wp[j] + acc[j]);
        *reinterpret_cast<ushort8*>(Weff + (size_t)n * K + k8) = o;
    }
}

// ---------------------------------------------------------------------------
// GEMM: out[M,N] (fp32) = Xbf[M,K] @ Weffbf[N,K]^T + bias (fp32)
//
// LDS regions (16 KB each, 128 KiB total):
//   Sa[buf][mh]: A M-half. [wrH(2)][64 rows][64 cols bf16]; global rows
//                bm + wrH*128 + mh*64 + row.
//   Sb[buf][nh]: B N-half (wc-interleaved). [wcH(4)][32 rows][64 cols];
//                global rows bn + wcH*64 + nh*32 + row.
// Swizzle (involution, both sides): 16B slot ^= (region-local row)&7.
// Reads use row = ...+lrow with all other terms ==0 mod 8, so read-side
// XOR term is (lrow&7); 8 lanes per 16B slot group == R6's measured-0-
// conflict density.
//
// 8 phases / 2 K-tiles (t->buf0, t+1->buf1), Gray quadrant order per tile
// (m0n0, m0n1, m1n1, m1n0) => every region's read window = 2 phases.
// Phase p: [ds_read frags (af reused across consecutive nh phases)]
//          [stage exactly 1 half-tile (2 gload_lds)]
//          BAR; lgkmcnt(0); setprio(1); 16 MFMA (8 dependent ks-pairs);
//          setprio(0); [P4,P8 only: vmcnt(4)]; BAR.
// Stage slots (steady state, hand-verified region liveness + coverage):
//   P1: B-n0(t+1)  P2: A-m1(t+1)  P3: A-m0(t+2)  P4: B-n1(t+2) +vmcnt(4)
//   P5: B-n0(t+2)  P6: A-m1(t+2)  P7: A-m0(t+3)  P8: B-n1(t+3) +vmcnt(4)
// Each vmcnt(4) retires exactly the 4 half-tiles the next 4 phases read;
// min stage->read lead = 4 phases; in-flight never exceeds 6 half-tiles.
// ---------------------------------------------------------------------------
#define BAR()       __builtin_amdgcn_s_barrier()
#define WAIT_LGKM() asm volatile("s_waitcnt lgkmcnt(0)" ::: "memory")
#define WAIT_VM4()  asm volatile("s_waitcnt vmcnt(4)" ::: "memory")
#define WAIT_VM0()  asm volatile("s_waitcnt vmcnt(0)" ::: "memory")

#define STAGE_A(buf, mh, kt) do {                                             \
    gload_lds16(gA0 + (size_t)(mh) * 64 * K + (kt) * 64, &Sa[buf][mh][c0 * 8]); \
    gload_lds16(gA1 + (size_t)(mh) * 64 * K + (kt) * 64, &Sa[buf][mh][c1 * 8]); \
} while (0)

#define STAGE_B(buf, nh, kt) do {                                             \
    gload_lds16(gB0 + (size_t)(nh) * 32 * K + (kt) * 64, &Sb[buf][nh][c0 * 8]); \
    gload_lds16(gB1 + (size_t)(nh) * 32 * K + (kt) * 64, &Sb[buf][nh][c1 * 8]); \
} while (0)

#define READ_A(buf, mh) do {                                                  \
    const unsigned short* ra = &Sa[buf][mh][(wr * 64 + lrow) * 64];           \
    _Pragma("unroll")                                                         \
    for (int mq = 0; mq < 4; ++mq) {                                          \
        af[0][mq] = *reinterpret_cast<const bf16x8*>(ra + mq * 1024 + swz0);  \
        af[1][mq] = *reinterpret_cast<const bf16x8*>(ra + mq * 1024 + swz1);  \
    }                                                                         \
} while (0)

#define READ_B(buf, nh) do {                                                  \
    const unsigned short* rb = &Sb[buf][nh][(wc * 32 + lrow) * 64];           \
    _Pragma("unroll")                                                         \
    for (int nq = 0; nq < 2; ++nq) {                                          \
        bq[0][nq] = *reinterpret_cast<const bf16x8*>(rb + nq * 1024 + swz0);  \
        bq[1][nq] = *reinterpret_cast<const bf16x8*>(rb + nq * 1024 + swz1);  \
    }                                                                         \
} while (0)

#define MFMAQ(mh, nh) do {                                                    \
    __builtin_amdgcn_s_setprio(1);                                            \
    _Pragma("unroll")                                                         \
    for (int mq = 0; mq < 4; ++mq)                                            \
        _Pragma("unroll")                                                     \
        for (int nq = 0; nq < 2; ++nq) {                                      \
            floatx4 tmp = __builtin_amdgcn_mfma_f32_16x16x32_bf16(            \
                af[0][mq], bq[0][nq], acc[(mh)*4+mq][(nh)*2+nq], 0, 0, 0);    \
            acc[(mh)*4+mq][(nh)*2+nq] = __builtin_amdgcn_mfma_f32_16x16x32_bf16( \
                af[1][mq], bq[1][nq], tmp, 0, 0, 0);                          \
        }                                                                     \
    __builtin_amdgcn_s_setprio(0);                                            \
} while (0)

__global__ __launch_bounds__(512)
void gemm_bias_kernel(const unsigned short* __restrict__ X,
                      const unsigned short* __restrict__ Wt,
                      const float* __restrict__ bias,
                      float* __restrict__ out)
{
    const int N = 2048, K = 2048;

    __shared__ alignas(16) unsigned short Sa[2][2][8192];   // 64 KB
    __shared__ alignas(16) unsigned short Sb[2][2][8192];   // 64 KB

    const int tid  = threadIdx.x;
    const int wave = tid >> 6;
    const int lane = tid & 63;
    const int lrow = lane & 15;
    const int quad = lane >> 4;
    const int wr   = wave >> 2;   // 0..1  (M split)
    const int wc   = wave & 3;    // 0..3  (N split)

    // XCD-rectangle swizzle (bijective, 256 % 8 == 0): XCD k owns m-stripes
    // [4k, 4k+4) x all 8 n-tiles => per-XCD X footprint 4 MB (fits its L2).
    const int id  = blockIdx.x;            // 0..255
    const int xcd = id & 7;
    const int sg  = id >> 3;               // 0..31
    const int bm  = (xcd * 4 + (sg & 3)) * BM;
    const int bn  = (sg >> 2) * BN;

    // Staging geometry. A half-tile granule c: wrH=c>>9, row=(c>>3)&63,
    // slot=c&7; LDS dest linear at c*16B; global col pre-swizzled.
    const int c0 = tid, c1 = tid + 512;
    const int ar0 = (c0 >> 3) & 63, as0 = c0 & 7;
    const int ar1 = (c1 >> 3) & 63, as1 = c1 & 7;
    const unsigned short* gA0 = X + (size_t)(bm + (c0 >> 9) * 128 + ar0) * K
                                  + ((as0 ^ (ar0 & 7)) << 3);
    const unsigned short* gA1 = X + (size_t)(bm + (c1 >> 9) * 128 + ar1) * K
                                  + ((as1 ^ (ar1 & 7)) << 3);
    // B half-tile granule c: wcH=c>>8, row=(c>>3)&31, slot=c&7.
    const int br0 = (c0 >> 3) & 31, br1 = (c1 >> 3) & 31;
    const unsigned short* gB0 = Wt + (size_t)(bn + (c0 >> 8) * 64 + br0) * K
                                   + ((as0 ^ (br0 & 7)) << 3);
    const unsigned short* gB1 = Wt + (size_t)(bn + (c1 >> 8) * 64 + br1) * K
                                   + ((as1 ^ (br1 & 7)) << 3);

    // ds_read swizzle: logical 16B granule g = ks*4+quad, phys = g^(lrow&7);
    // ks flips bit2 only => swz1 = swz0 ^ 32 (ushorts).
    const int swz0 = (quad ^ (lrow & 7)) << 3;
    const int swz1 = swz0 ^ 32;

    floatx4 acc[8][4] = {};
    bf16x8 af[2][4];   // [ks][m-frag] — reused across consecutive nh phases
    bf16x8 bq[2][2];   // [ks][n-frag]

    // Prologue: tile0 (buf0) all 4 half-tiles, then A-m0(1), B-n1(1).
    // vmcnt(4) leaves exactly the last two in flight == steady-state entry.
    STAGE_A(0, 0, 0);
    STAGE_B(0, 1, 0);
    STAGE_B(0, 0, 0);
    STAGE_A(0, 1, 0);
    STAGE_A(1, 0, 1);
    STAGE_B(1, 1, 1);
    WAIT_VM4(); BAR();

#pragma unroll 1
    for (int tt = 0; tt < NT; tt += 2) {
        const int t1 = tt + 1;
        const int t2 = (tt + 2 < NT) ? tt + 2 : NT - 1;   // clamped tail stages
        const int t3 = (tt + 3 < NT) ? tt + 3 : NT - 1;   // land in dead regions

        // ---- tile t (buf0) ----
        // P1 (m0,n0)
        READ_A(0, 0); READ_B(0, 0);
        STAGE_B(1, 0, t1);
        BAR(); WAIT_LGKM(); MFMAQ(0, 0); BAR();
        // P2 (m0,n1)
        READ_B(0, 1);
        STAGE_A(1, 1, t1);
        BAR(); WAIT_LGKM(); MFMAQ(0, 1); BAR();
        // P3 (m1,n1)
        READ_A(0, 1);
        STAGE_A(0, 0, t2);
        BAR(); WAIT_LGKM(); MFMAQ(1, 1); BAR();
        // P4 (m1,n0)
        READ_B(0, 0);
        STAGE_B(0, 1, t2);
        BAR(); WAIT_LGKM(); MFMAQ(1, 0); WAIT_VM4(); BAR();

        // ---- tile t+1 (buf1) ----
        // P5 (m0,n0)
        READ_A(1, 0); READ_B(1, 0);
        STAGE_B(0, 0, t2);
        BAR(); WAIT_LGKM(); MFMAQ(0, 0); BAR();
        // P6 (m0,n1)
        READ_B(1, 1);
        STAGE_A(0, 1, t2);
        BAR(); WAIT_LGKM(); MFMAQ(0, 1); BAR();
        // P7 (m1,n1)
        READ_A(1, 1);
        STAGE_A(1, 0, t3);
        BAR(); WAIT_LGKM(); MFMAQ(1, 1); BAR();
        // P8 (m1,n0)
        READ_B(1, 0);
        STAGE_B(1, 1, t3);
        BAR(); WAIT_LGKM(); MFMAQ(1, 0); WAIT_VM4(); BAR();
    }
    WAIT_VM0();   // drain tail stages before endpgm

    // Epilogue. C/D layout (m89/m91): col = lane&15, row = (lane>>4)*4 + reg.
    // acc[mi][ni]: global row = bm + wr*128 + (mi>>2)*64 + (mi&3)*16 + quad*4+r,
    //              global col = bn + wc*64 + (ni>>1)*32 + (ni&1)*16 + lrow.
    float bsv[4];
#pragma unroll
    for (int ni = 0; ni < 4; ++ni)
        bsv[ni] = bias[bn + wc * 64 + (ni >> 1) * 32 + (ni & 1) * 16 + lrow];

    const int rbase = quad << 2;
#pragma unroll
    for (int mi = 0; mi < 8; ++mi) {
#pragma unroll
        for (int r = 0; r < 4; ++r) {
            size_t rowoff = (size_t)(bm + wr * 128 + (mi >> 2) * 64
                                     + (mi & 3) * 16 + rbase + r) * N;
#pragma unroll
            for (int ni = 0; ni < 4; ++ni)
                out[rowoff + bn + wc * 64 + (ni >> 1) * 32 + (ni & 1) * 16 + lrow]
                    = acc[mi][ni][r] + bsv[ni];
        }
    }
}

extern "C" void kernel_launch(void* const* d_in, const int* in_sizes, int n_in,
                              void* d_out, int out_size, void* d_ws, size_t ws_size,
                              hipStream_t stream)
{
    const float* x  = (const float*)d_in[0];
    const float* W  = (const float*)d_in[1];
    const float* b  = (const float*)d_in[2];
    const float* A  = (const float*)d_in[3];
    const float* Bm = (const float*)d_in[4];
    const float* sc = (const float*)d_in[5];
    float* out = (float*)d_out;

    const size_t M = 8192, N = 2048, K = 2048;

    unsigned short* Xbf  = (unsigned short*)d_ws;                 // 32 MB
    unsigned short* Weff = (unsigned short*)d_ws + M * K;         // + 8 MB

    // 1) fused: Xbf = bf16(x); Weff = bf16(W + scale * B@A)
    aux_kernel<<<dim3((M * K + N * K) / 8 / 256), dim3(256), 0, stream>>>(
        x, Xbf, W, A, Bm, sc, Weff);

    // 2) out = Xbf @ Weff^T + b  (fp32 out), 256 blocks = 256 CUs, no tails
    gemm_bias_kernel<<<dim3((M / BM) * (N / BN)), dim3(512), 0, stream>>>(
        Xbf, Weff, b, out);
}